// Round 17
// baseline (71.580 us; speedup 1.0000x reference)
//
#include <hip/hip_runtime.h>

#define DM    1024
#define NTOK  32768   // B*S
#define NRED  16384
#define NSAVE 16384
#define MMAX  16384   // max compacted rows
#define AS1 __attribute__((address_space(1)))
#define AS3 __attribute__((address_space(3)))

typedef __attribute__((ext_vector_type(8))) short bf16x8;
typedef __attribute__((ext_vector_type(4))) float f32x4;

__device__ __forceinline__ ushort f2bf(float f) {
    union { float f; unsigned u; } v; v.f = f;
    unsigned r = (v.u + 0x7FFF + ((v.u >> 16) & 1)) >> 16;   // RNE
    return (ushort)r;
}
__device__ __forceinline__ float bf2f(ushort u) {
    union { unsigned u; float f; } v; v.u = ((unsigned)u) << 16;
    return v.f;
}

// ---------------------------------------------------------------------------
__global__ __launch_bounds__(256) void setup_kernel(const float* __restrict__ W,
                                                    ushort* __restrict__ Wb,
                                                    int* __restrict__ cnt,
                                                    int* __restrict__ need,
                                                    int* __restrict__ counter) {
    int t = blockIdx.x * 256 + threadIdx.x;
    float4 v = ((const float4*)W)[t];
    ushort4 o;
    o.x = f2bf(v.x); o.y = f2bf(v.y); o.z = f2bf(v.z); o.w = f2bf(v.w);
    ((ushort4*)Wb)[t] = o;
    if (t < NTOK) { cnt[t] = 0; need[t] = 0; }
    if (t == 0) *counter = 0;
}

// ---------------------------------------------------------------------------
__global__ __launch_bounds__(256) void prep_kernel(const int* __restrict__ red,
                                                   const int* __restrict__ sav,
                                                   int* __restrict__ cnt,
                                                   int* __restrict__ need) {
    int j = blockIdx.x * 256 + threadIdx.x;
    if (j >= NRED) return;
    atomicAdd(&cnt[red[j]], 1);
    int s = sav[j];
    if (s > 0) need[s - 1] = 1;
}

// ---------------------------------------------------------------------------
__global__ __launch_bounds__(256) void compact_kernel(const int* __restrict__ cnt,
                                                      const int* __restrict__ need,
                                                      int* __restrict__ inv,
                                                      int* __restrict__ list,
                                                      int* __restrict__ counter) {
    int t = blockIdx.x * 256 + threadIdx.x;
    if (t >= NTOK) return;
    if (need[t] && cnt[t] > 0) {
        int pos = atomicAdd(counter, 1);
        inv[t] = pos;
        list[pos] = t;
    }
}

// ---------------------------------------------------------------------------
// convx: gather + fp32->bf16 convert compacted rows; zero-pad to 256 multiple
// ---------------------------------------------------------------------------
__global__ __launch_bounds__(256) void convx_kernel(const float* __restrict__ X,
                                                    const int* __restrict__ list,
                                                    const int* __restrict__ counter,
                                                    ushort* __restrict__ Xb) {
    const int M = *counter;
    const int Mpad = (M + 255) & ~255;
    for (int r = blockIdx.x; r < Mpad; r += gridDim.x) {
        ushort4 o;
        if (r < M) {
            int src = list[r];
            float4 v = ((const float4*)(X + (size_t)src * DM))[threadIdx.x];
            o.x = f2bf(v.x); o.y = f2bf(v.y); o.z = f2bf(v.z); o.w = f2bf(v.w);
        } else {
            o.x = 0; o.y = 0; o.z = 0; o.w = 0;
        }
        ((ushort4*)(Xb + (size_t)r * DM))[threadIdx.x] = o;
    }
}

// ---------------------------------------------------------------------------
// 8-phase-class 256x256 bf16 MFMA GEMM, split-K=2.
// Tp[z][m,n] = bf16( sum_{k in window z} Xb[m,k]*Wb[n,k] )
// 8 waves (512 thr), wave (wr,wn) = 128x64 output block (8x4 frags 16x16x32).
// Per K-tile (BK=64): 4 phases = C-quadrants (m0n0),(m0n1),(m1n0),(m1n1);
// A-frags cached across each n-pair. Each phase stages ONE half-tile of the
// NEXT K-tile into the other LDS buffer (A0@p0, B0@p1, A1@p2, B1@p3) -- each
// target region's last reads are >=2 barrier-gaps earlier (race-checked).
// Counted waits: vmcnt(6)@p0, vmcnt(4)@p1 only (loads stay in flight, T4).
// One s_barrier per phase; lgkmcnt(0)+sched_barrier before MFMA (rule #18);
// setprio around MFMA (T5, 8-wave role diversity). LDS: 2 x 64 KB dynamic.
// Swizzle: R7's measured-0-conflict chunk^=(row&7), pre-swizzled gload src
// (rule #21). A halves = 64-row bands per m-half; B halves = 32-row stripes
// per n-half (exactly the rows each quadrant consumes).
// ---------------------------------------------------------------------------
__global__ __launch_bounds__(512) void gemm_kernel(const ushort* __restrict__ Xb,
                                                   const ushort* __restrict__ Wb,
                                                   const int* __restrict__ counter,
                                                   ushort* __restrict__ Tp) {
    const int M = *counter;
    const int m0 = blockIdx.x * 256;
    if (m0 >= M) return;                 // uniform exit before any barrier
    const int n0 = blockIdx.y * 256;
    const int kw = blockIdx.z;
    ushort* Tout = Tp + (size_t)kw * ((size_t)MMAX * DM);

    extern __shared__ char lds[];        // 131072 = 2 bufs x (A 32K + B 32K)

    const int tid = threadIdx.x;
    const int l   = tid & 63;
    const int wid = tid >> 6;            // 0..7
    const int wr  = wid >> 2;            // 0..1
    const int wn  = wid & 3;             // 0..3
    const int tr  = tid >> 3;            // 0..63
    const int ch  = (tid & 7) ^ (tr & 7);    // pre-swizzled source chunk

    // staging source pointers (A: 64-row bands; B: 32-row stripes)
    const ushort* aP0 = Xb + (size_t)(m0 + tr) * DM + ch * 8;
    const ushort* aP1 = aP0 + (size_t)128 * DM;
    const int brr = (tr < 32) ? tr : (tr + 32);
    const ushort* bP0 = Wb + (size_t)(n0 + brr) * DM + ch * 8;
    const ushort* bP1 = bP0 + (size_t)128 * DM;

    // wave-uniform LDS dest bases (gload_lds scatters lane*16 itself)
    const int adb = wid * 8 * 128;                                   // + i*16384 + h*8192
    const int bdb = 32768 + ((wid >> 2) * 64 + (wid & 3) * 8) * 128; // + i*16384 + h*4096

#define STG_A(nb, h, kn) do {                                                         \
    __builtin_amdgcn_global_load_lds((const AS1 unsigned*)(aP0 + (h) * 64 * DM + (kn)), \
        (AS3 unsigned*)(lds + (nb) + adb + (h) * 8192), 16, 0, 0);                    \
    __builtin_amdgcn_global_load_lds((const AS1 unsigned*)(aP1 + (h) * 64 * DM + (kn)), \
        (AS3 unsigned*)(lds + (nb) + adb + 16384 + (h) * 8192), 16, 0, 0);            \
} while (0)
#define STG_B(nb, h, kn) do {                                                         \
    __builtin_amdgcn_global_load_lds((const AS1 unsigned*)(bP0 + (h) * 32 * DM + (kn)), \
        (AS3 unsigned*)(lds + (nb) + bdb + (h) * 4096), 16, 0, 0);                    \
    __builtin_amdgcn_global_load_lds((const AS1 unsigned*)(bP1 + (h) * 32 * DM + (kn)), \
        (AS3 unsigned*)(lds + (nb) + bdb + 16384 + (h) * 4096), 16, 0, 0);            \
} while (0)

    // fragment read bases (global-row minus origin == LDS row; same XOR)
    const int kg  = l >> 4;
    const int r16 = l & 15;
    const int c0 = ((kg ^ (r16 & 7)) << 4);
    const int c1 = (((4 + kg) ^ (r16 & 7)) << 4);
    int arb[8], brb[4];
#pragma unroll
    for (int f = 0; f < 8; ++f) arb[f] = (wr * 128 + f * 16 + r16) * 128;
#pragma unroll
    for (int f = 0; f < 4; ++f) brb[f] = 32768 + (wn * 64 + f * 16 + r16) * 128;

    f32x4 acc[8][4] = {};
    bf16x8 af[4][2];

    const int kb = kw * 512;             // this z-window: K columns [kb, kb+512)
    // prologue: stage tile 0's 4 halves into buf0 (order A0,B0,A1,B1)
    STG_A(0, 0, kb); STG_B(0, 0, kb); STG_A(0, 1, kb); STG_B(0, 1, kb);

#pragma unroll 2
    for (int krel = 0; krel < 8; ++krel) {
        const int cb = (krel & 1) * 65536;
        const int nb = cb ^ 65536;
        const int kn = kb + ((krel < 7) ? (krel + 1) : krel) * 64;  // last tile: benign restage

        // ======== phase 0: (m-half0, n-half0); stage next.A0 ========
        STG_A(nb, 0, kn);
        asm volatile("s_waitcnt vmcnt(6)" ::: "memory");   // cur A0,B0 landed (mine)
        __builtin_amdgcn_sched_barrier(0);
        __builtin_amdgcn_s_barrier();                      // landed for ALL waves
        {
            bf16x8 bf[2][2];
#pragma unroll
            for (int fm = 0; fm < 4; ++fm) {
                af[fm][0] = *(const bf16x8*)(lds + cb + arb[fm] + c0);
                af[fm][1] = *(const bf16x8*)(lds + cb + arb[fm] + c1);
            }
#pragma unroll
            for (int fn = 0; fn < 2; ++fn) {
                bf[fn][0] = *(const bf16x8*)(lds + cb + brb[fn] + c0);
                bf[fn][1] = *(const bf16x8*)(lds + cb + brb[fn] + c1);
            }
            asm volatile("s_waitcnt lgkmcnt(0)" ::: "memory");
            __builtin_amdgcn_sched_barrier(0);
            __builtin_amdgcn_s_setprio(1);
#pragma unroll
            for (int fm = 0; fm < 4; ++fm)
#pragma unroll
                for (int fn = 0; fn < 2; ++fn) {
                    acc[fm][fn] = __builtin_amdgcn_mfma_f32_16x16x32_bf16(af[fm][0], bf[fn][0], acc[fm][fn], 0, 0, 0);
                    acc[fm][fn] = __builtin_amdgcn_mfma_f32_16x16x32_bf16(af[fm][1], bf[fn][1], acc[fm][fn], 0, 0, 0);
                }
            __builtin_amdgcn_s_setprio(0);
        }
        // ======== phase 1: (m-half0, n-half1); stage next.B0 ========
        STG_B(nb, 0, kn);
        asm volatile("s_waitcnt vmcnt(4)" ::: "memory");   // cur A1,B1 landed (mine)
        __builtin_amdgcn_sched_barrier(0);
        __builtin_amdgcn_s_barrier();
        {
            bf16x8 bf[2][2];
#pragma unroll
            for (int fn = 0; fn < 2; ++fn) {
                bf[fn][0] = *(const bf16x8*)(lds + cb + brb[2 + fn] + c0);
                bf[fn][1] = *(const bf16x8*)(lds + cb + brb[2 + fn] + c1);
            }
            asm volatile("s_waitcnt lgkmcnt(0)" ::: "memory");
            __builtin_amdgcn_sched_barrier(0);
            __builtin_amdgcn_s_setprio(1);
#pragma unroll
            for (int fm = 0; fm < 4; ++fm)
#pragma unroll
                for (int fn = 0; fn < 2; ++fn) {
                    acc[fm][2 + fn] = __builtin_amdgcn_mfma_f32_16x16x32_bf16(af[fm][0], bf[fn][0], acc[fm][2 + fn], 0, 0, 0);
                    acc[fm][2 + fn] = __builtin_amdgcn_mfma_f32_16x16x32_bf16(af[fm][1], bf[fn][1], acc[fm][2 + fn], 0, 0, 0);
                }
            __builtin_amdgcn_s_setprio(0);
        }
        // ======== phase 2: (m-half1, n-half0); stage next.A1 ========
        STG_A(nb, 1, kn);
        __builtin_amdgcn_sched_barrier(0);
        __builtin_amdgcn_s_barrier();
        {
            bf16x8 bf[2][2];
#pragma unroll
            for (int fm = 0; fm < 4; ++fm) {
                af[fm][0] = *(const bf16x8*)(lds + cb + arb[4 + fm] + c0);
                af[fm][1] = *(const bf16x8*)(lds + cb + arb[4 + fm] + c1);
            }
#pragma unroll
            for (int fn = 0; fn < 2; ++fn) {
                bf[fn][0] = *(const bf16x8*)(lds + cb + brb[fn] + c0);
                bf[fn][1] = *(const bf16x8*)(lds + cb + brb[fn] + c1);
            }
            asm volatile("s_waitcnt lgkmcnt(0)" ::: "memory");
            __builtin_amdgcn_sched_barrier(0);
            __builtin_amdgcn_s_setprio(1);
#pragma unroll
            for (int fm = 0; fm < 4; ++fm)
#pragma unroll
                for (int fn = 0; fn < 2; ++fn) {
                    acc[4 + fm][fn] = __builtin_amdgcn_mfma_f32_16x16x32_bf16(af[fm][0], bf[fn][0], acc[4 + fm][fn], 0, 0, 0);
                    acc[4 + fm][fn] = __builtin_amdgcn_mfma_f32_16x16x32_bf16(af[fm][1], bf[fn][1], acc[4 + fm][fn], 0, 0, 0);
                }
            __builtin_amdgcn_s_setprio(0);
        }
        // ======== phase 3: (m-half1, n-half1); stage next.B1 ========
        STG_B(nb, 1, kn);
        __builtin_amdgcn_sched_barrier(0);
        __builtin_amdgcn_s_barrier();
        {
            bf16x8 bf[2][2];
#pragma unroll
            for (int fn = 0; fn < 2; ++fn) {
                bf[fn][0] = *(const bf16x8*)(lds + cb + brb[2 + fn] + c0);
                bf[fn][1] = *(const bf16x8*)(lds + cb + brb[2 + fn] + c1);
            }
            asm volatile("s_waitcnt lgkmcnt(0)" ::: "memory");
            __builtin_amdgcn_sched_barrier(0);
            __builtin_amdgcn_s_setprio(1);
#pragma unroll
            for (int fm = 0; fm < 4; ++fm)
#pragma unroll
                for (int fn = 0; fn < 2; ++fn) {
                    acc[4 + fm][2 + fn] = __builtin_amdgcn_mfma_f32_16x16x32_bf16(af[fm][0], bf[fn][0], acc[4 + fm][2 + fn], 0, 0, 0);
                    acc[4 + fm][2 + fn] = __builtin_amdgcn_mfma_f32_16x16x32_bf16(af[fm][1], bf[fn][1], acc[4 + fm][2 + fn], 0, 0, 0);
                }
            __builtin_amdgcn_s_setprio(0);
        }
    }
    asm volatile("s_waitcnt vmcnt(0)" ::: "memory");   // drain benign restage before endpgm
#undef STG_A
#undef STG_B

    // C/D layout: col = lane&15, row = (lane>>4)*4 + reg  [m89]
#pragma unroll
    for (int fm = 0; fm < 8; ++fm) {
        int mbase = m0 + wr * 128 + fm * 16 + kg * 4;
#pragma unroll
        for (int fn = 0; fn < 4; ++fn) {
            int n = n0 + wn * 64 + fn * 16 + r16;
#pragma unroll
            for (int r = 0; r < 4; ++r) {
                int m = mbase + r;
                if (m < M) Tout[(size_t)m * DM + n] = f2bf(acc[fm][fn][r]);
            }
        }
    }
}

// ---------------------------------------------------------------------------
// epilogue: out[r] = x[s] + cnt[s-1] * (Tp0[inv[s-1]] + Tp1[inv[s-1]])
// ---------------------------------------------------------------------------
__global__ __launch_bounds__(256) void out_kernel(const float* __restrict__ X,
                                                  const ushort* __restrict__ Tp,
                                                  const int* __restrict__ sav,
                                                  const int* __restrict__ cnt,
                                                  const int* __restrict__ inv,
                                                  float* __restrict__ out) {
    int r = blockIdx.x;
    int d = threadIdx.x;                 // float4 lane, 0..255
    int s = sav[r];
    const float4* xr = (const float4*)(X + (size_t)s * DM);
    float4 v = xr[d];
    if (s > 0) {
        int t = s - 1;
        int c = cnt[t];
        if (c > 0) {
            float fc = (float)c;
            size_t rowoff = (size_t)inv[t] * DM;
            ushort4 p0 = ((const ushort4*)(Tp + rowoff))[d];
            ushort4 p1 = ((const ushort4*)(Tp + (size_t)MMAX * DM + rowoff))[d];
            v.x += fc * (bf2f(p0.x) + bf2f(p1.x));
            v.y += fc * (bf2f(p0.y) + bf2f(p1.y));
            v.z += fc * (bf2f(p0.z) + bf2f(p1.z));
            v.w += fc * (bf2f(p0.w) + bf2f(p1.w));
        }
    }
    ((float4*)out)[(size_t)r * (DM / 4) + d] = v;
}

// ---------------------------------------------------------------------------
extern "C" void kernel_launch(void* const* d_in, const int* in_sizes, int n_in,
                              void* d_out, int out_size, void* d_ws, size_t ws_size,
                              hipStream_t stream) {
    const float* X   = (const float*)d_in[0];
    const float* W   = (const float*)d_in[1];
    const int*   sav = (const int*)d_in[2];   // ids_to_save
    const int*   red = (const int*)d_in[3];   // ids_to_reduce
    float* out = (float*)d_out;

    char* ws = (char*)d_ws;
    int* counter = (int*)ws;                  // 64 ints
    int* cnt  = counter + 64;                 // 32768
    int* need = cnt + NTOK;                   // 32768
    int* inv  = need + NTOK;                  // 32768
    int* list = inv + NTOK;                   // 16384  (ends < 512 KB)
    ushort* Wb = (ushort*)(ws + (1 << 19));   // 2 MB bf16 W
    ushort* Xb = (ushort*)(ws + (4 << 20));   // 32 MB bf16 compacted X rows (padded)
    ushort* Tp = (ushort*)(ws + (36u << 20)); // 2 x 32 MB bf16 split-K partials

    setup_kernel<<<DM * DM / 4 / 256, 256, 0, stream>>>(W, Wb, cnt, need, counter);
    prep_kernel<<<NRED / 256, 256, 0, stream>>>(red, sav, cnt, need);
    compact_kernel<<<NTOK / 256, 256, 0, stream>>>(cnt, need, inv, list, counter);
    convx_kernel<<<2048, 256, 0, stream>>>(X, list, counter, Xb);

    dim3 ggrid(MMAX / 256, DM / 256, 2);      // x = m-blocks (64, early-exit), y = n (4), z = K-split
    gemm_kernel<<<ggrid, 512, 131072, stream>>>(Xb, Wb, counter, Tp);

    out_kernel<<<NSAVE, 256, 0, stream>>>(X, Tp, sav, cnt, inv, out);
}